// Round 1
// baseline (8810.014 us; speedup 1.0000x reference)
//
#include <hip/hip_runtime.h>
#include <math.h>

#define N_NODES 1200000
#define N_EDGES 12000000
#define D_IN    10
#define D_H     20
#define D_ENCC  5
#define VECC    6
#define B_ROWS  200000

__device__ __forceinline__ float gelu_exact(float x) {
    return 0.5f * x * (1.0f + erff(x * 0.70710678118654752f));
}

// ---- degree via atomics --------------------------------------------------
__global__ void k_deg(const int* __restrict__ dst, float* __restrict__ deg) {
    int e = blockIdx.x * blockDim.x + threadIdx.x;
    if (e < N_EDGES) atomicAdd(&deg[dst[e]], 1.0f);
}

__global__ void k_dinv(float* __restrict__ deg_dinv) {
    int i = blockIdx.x * blockDim.x + threadIdx.x;
    if (i < N_NODES) deg_dinv[i] = rsqrtf(deg_dinv[i] + 1.0f);
}

// ---- hs1 = ((x + po) @ W1) * dinv ; acc1 = hs1 (self-loop term) ----------
__global__ void k_h1(const float* __restrict__ x, const float* __restrict__ W1,
                     const float* __restrict__ dinv,
                     float* __restrict__ hs1, float* __restrict__ acc1) {
    __shared__ float sW[D_IN * D_H];
    __shared__ float spo[D_IN];
    for (int t = threadIdx.x; t < D_IN * D_H; t += blockDim.x) sW[t] = W1[t];
    if (threadIdx.x < D_IN) spo[threadIdx.x] = sinf((float)threadIdx.x);
    __syncthreads();
    int i = blockIdx.x * blockDim.x + threadIdx.x;
    if (i >= N_NODES) return;
    float xi[D_IN];
#pragma unroll
    for (int k = 0; k < D_IN; k++) xi[k] = x[i * D_IN + k] + spo[k];
    float di = dinv[i];
#pragma unroll
    for (int j = 0; j < D_H; j++) {
        float a = 0.f;
#pragma unroll
        for (int k = 0; k < D_IN; k++) a += xi[k] * sW[k * D_H + j];
        a *= di;
        hs1[i * D_H + j]  = a;
        acc1[i * D_H + j] = a;
    }
}

// ---- GCN1 scatter: one thread per (edge, float4 chunk of 20) -------------
__global__ void k_sc1(const int* __restrict__ src, const int* __restrict__ dst,
                      const float* __restrict__ hs1, float* __restrict__ acc1) {
    int t = blockIdx.x * blockDim.x + threadIdx.x;
    if (t >= N_EDGES * 5) return;
    int e = t / 5;
    int c = t - e * 5;
    int s = src[e], d = dst[e];
    const float4 v = *(const float4*)(hs1 + (size_t)s * D_H + c * 4);
    float* p = acc1 + (size_t)d * D_H + c * 4;
    atomicAdd(p + 0, v.x);
    atomicAdd(p + 1, v.y);
    atomicAdd(p + 2, v.z);
    atomicAdd(p + 3, v.w);
}

// ---- h2pre = gelu(dinv*acc1 + b1); hs2 = (h2pre @ W2)*dinv; acc2 = hs2 ---
__global__ void k_h2(const float* __restrict__ acc1, const float* __restrict__ dinv,
                     const float* __restrict__ W2, const float* __restrict__ b1,
                     float* __restrict__ hs2, float* __restrict__ acc2) {
    __shared__ float sW[D_H * D_ENCC];
    __shared__ float sb1[D_H];
    int tx = threadIdx.x;
    if (tx < D_H * D_ENCC) sW[tx] = W2[tx];
    if (tx < D_H) sb1[tx] = b1[tx];
    __syncthreads();
    int i = blockIdx.x * blockDim.x + threadIdx.x;
    if (i >= N_NODES) return;
    float di = dinv[i];
    float tf[D_H];
#pragma unroll
    for (int f = 0; f < D_H; f++)
        tf[f] = gelu_exact(di * acc1[i * D_H + f] + sb1[f]);
#pragma unroll
    for (int c = 0; c < D_ENCC; c++) {
        float a = 0.f;
#pragma unroll
        for (int f = 0; f < D_H; f++) a += tf[f] * sW[f * D_ENCC + c];
        a *= di;
        hs2[i * D_ENCC + c]  = a;
        acc2[i * D_ENCC + c] = a;
    }
}

// ---- GCN2 scatter: one thread per edge, 5 atomics ------------------------
__global__ void k_sc2(const int* __restrict__ src, const int* __restrict__ dst,
                      const float* __restrict__ hs2, float* __restrict__ acc2) {
    int e = blockIdx.x * blockDim.x + threadIdx.x;
    if (e >= N_EDGES) return;
    int s = src[e], d = dst[e];
#pragma unroll
    for (int c = 0; c < D_ENCC; c++)
        atomicAdd(&acc2[(size_t)d * D_ENCC + c], hs2[(size_t)s * D_ENCC + c]);
}

// ---- dense tail: h2 on the fly, then enc / out / x1 ----------------------
__global__ void k_dense(const float* __restrict__ acc2, const float* __restrict__ dinv,
                        const float* __restrict__ b2,
                        const float* __restrict__ We, const float* __restrict__ be,
                        const float* __restrict__ Wd, const float* __restrict__ bd,
                        const float* __restrict__ Wr, const float* __restrict__ br,
                        float* __restrict__ out) {
    __shared__ float sWe[900], sWd[1800], sWr[210];
    __shared__ float sbe[30], sbd[60], sbr[7], sb2[5];
    for (int t = threadIdx.x; t < 900;  t += blockDim.x) sWe[t] = We[t];
    for (int t = threadIdx.x; t < 1800; t += blockDim.x) sWd[t] = Wd[t];
    for (int t = threadIdx.x; t < 210;  t += blockDim.x) sWr[t] = Wr[t];
    if (threadIdx.x < 30) sbe[threadIdx.x] = be[threadIdx.x];
    if (threadIdx.x >= 64  && threadIdx.x < 124) sbd[threadIdx.x - 64]  = bd[threadIdx.x - 64];
    if (threadIdx.x >= 128 && threadIdx.x < 135) sbr[threadIdx.x - 128] = br[threadIdx.x - 128];
    if (threadIdx.x >= 192 && threadIdx.x < 197) sb2[threadIdx.x - 192] = b2[threadIdx.x - 192];
    __syncthreads();
    int b = blockIdx.x * blockDim.x + threadIdx.x;
    if (b >= B_ROWS) return;

    // r[k] = gelu(dinv[n]*acc2[n,f] + b2[f]), n = 6b + k/5, f = k%5
    float r[30];
    int base = b * 30;  // == (6b)*5
#pragma unroll
    for (int k = 0; k < 30; k++) {
        int n = b * VECC + k / D_ENCC;
        int f = k % D_ENCC;
        r[k] = gelu_exact(dinv[n] * acc2[base + k] + sb2[f]);
    }

    float enc[30];
#pragma unroll
    for (int j = 0; j < 30; j++) {
        float a = sbe[j];
#pragma unroll
        for (int k = 0; k < 30; k++) a += r[k] * sWe[k * 30 + j];
        enc[j] = a;
    }

    float* x1o  = out;                 // [B,7]
    float* enco = out + (size_t)B_ROWS * 7;   // [B,30]
    float* outo = out + (size_t)B_ROWS * 37;  // [B,60]

#pragma unroll
    for (int j = 0; j < 30; j++) enco[(size_t)b * 30 + j] = enc[j];

    // reuse r for gelu(enc)
#pragma unroll
    for (int k = 0; k < 30; k++) r[k] = gelu_exact(enc[k]);
#pragma unroll
    for (int j = 0; j < 60; j++) {
        float a = sbd[j];
#pragma unroll
        for (int k = 0; k < 30; k++) a += r[k] * sWd[k * 60 + j];
        outo[(size_t)b * 60 + j] = a;
    }
#pragma unroll
    for (int j = 0; j < 7; j++) {
        float a = sbr[j];
#pragma unroll
        for (int k = 0; k < 30; k++) a += enc[k] * sWr[k * 7 + j];
        x1o[(size_t)b * 7 + j] = a;
    }
}

extern "C" void kernel_launch(void* const* d_in, const int* in_sizes, int n_in,
                              void* d_out, int out_size, void* d_ws, size_t ws_size,
                              hipStream_t stream) {
    const float* x   = (const float*)d_in[0];
    const int*   ei  = (const int*)d_in[1];
    const int*   src = ei;
    const int*   dst = ei + N_EDGES;
    const float* W1  = (const float*)d_in[2];
    const float* b1  = (const float*)d_in[3];
    const float* W2  = (const float*)d_in[4];
    const float* b2  = (const float*)d_in[5];
    const float* We  = (const float*)d_in[6];
    const float* be  = (const float*)d_in[7];
    const float* Wd  = (const float*)d_in[8];
    const float* bd  = (const float*)d_in[9];
    const float* Wr  = (const float*)d_in[10];
    const float* br  = (const float*)d_in[11];

    float* ws   = (float*)d_ws;
    float* dinv = ws;                               // N
    float* hs1  = dinv + N_NODES;                   // N*20
    float* acc1 = hs1  + (size_t)N_NODES * D_H;     // N*20
    float* hs2  = acc1 + (size_t)N_NODES * D_H;     // N*5
    float* acc2 = hs2  + (size_t)N_NODES * D_ENCC;  // N*5

    hipMemsetAsync(dinv, 0, (size_t)N_NODES * sizeof(float), stream);

    k_deg <<<(N_EDGES + 255) / 256, 256, 0, stream>>>(dst, dinv);
    k_dinv<<<(N_NODES + 255) / 256, 256, 0, stream>>>(dinv);
    k_h1  <<<(N_NODES + 255) / 256, 256, 0, stream>>>(x, W1, dinv, hs1, acc1);
    k_sc1 <<<(N_EDGES * 5 + 255) / 256, 256, 0, stream>>>(src, dst, hs1, acc1);
    k_h2  <<<(N_NODES + 255) / 256, 256, 0, stream>>>(acc1, dinv, W2, b1, hs2, acc2);
    k_sc2 <<<(N_EDGES + 255) / 256, 256, 0, stream>>>(src, dst, hs2, acc2);
    k_dense<<<(B_ROWS + 255) / 256, 256, 0, stream>>>(acc2, dinv, b2, We, be, Wd, bd,
                                                      Wr, br, (float*)d_out);
}

// Round 2
// 2060.810 us; speedup vs baseline: 4.2750x; 4.2750x over previous
//
#include <hip/hip_runtime.h>
#include <math.h>

#define N_NODES 1200000
#define N_EDGES 12000000
#define D_IN    10
#define D_H     20
#define D_ENCC  5
#define VECC    6
#define B_ROWS  200000
#define NB_SCAN 4688   // ceil(N_NODES / 256)

__device__ __forceinline__ float gelu_exact(float x) {
    return 0.5f * x * (1.0f + erff(x * 0.70710678118654752f));
}

// ---- degree count (int atomics) ------------------------------------------
__global__ void k_count(const int* __restrict__ dst, int* __restrict__ degi) {
    int e = blockIdx.x * blockDim.x + threadIdx.x;
    if (e < N_EDGES) atomicAdd(&degi[dst[e]], 1);
}

// ---- scan step 1: per-block exclusive scan + block sums ------------------
__global__ void k_scan1(const int* __restrict__ degi, int* __restrict__ excl,
                        int* __restrict__ bsum) {
    __shared__ int s[256];
    int tid = threadIdx.x;
    int i = blockIdx.x * 256 + tid;
    int v = (i < N_NODES) ? degi[i] : 0;
    s[tid] = v;
    __syncthreads();
    for (int off = 1; off < 256; off <<= 1) {
        int t = (tid >= off) ? s[tid - off] : 0;
        __syncthreads();
        s[tid] += t;
        __syncthreads();
    }
    if (i < N_NODES) excl[i] = s[tid] - v;   // exclusive within block
    if (tid == 255) bsum[blockIdx.x] = s[255];
}

// ---- scan step 2: scan the 4688 block sums (single block) ----------------
__global__ void k_scan2(const int* __restrict__ bsum, int* __restrict__ boff) {
    __shared__ int ls[NB_SCAN];
    __shared__ int ps[256];
    int tid = threadIdx.x;
    for (int t = tid; t < NB_SCAN; t += 256) ls[t] = bsum[t];
    __syncthreads();
    const int CH = (NB_SCAN + 255) / 256;  // 19
    int start = tid * CH;
    int end = start + CH; if (end > NB_SCAN) end = NB_SCAN;
    int sum = 0;
    for (int t = start; t < end && t < NB_SCAN; t++) sum += ls[t];
    ps[tid] = sum;
    __syncthreads();
    for (int off = 1; off < 256; off <<= 1) {
        int t = (tid >= off) ? ps[tid - off] : 0;
        __syncthreads();
        ps[tid] += t;
        __syncthreads();
    }
    int run = ps[tid] - sum;  // exclusive prefix of this chunk
    for (int t = start; t < end && t < NB_SCAN; t++) {
        boff[t] = run;
        run += ls[t];
    }
}

// ---- scan step 3: finalize rowptr, init fill, compute dinv ---------------
__global__ void k_scan3(const int* __restrict__ excl, const int* __restrict__ boff,
                        const int* __restrict__ degi,
                        int* __restrict__ rowptr, int* __restrict__ fill,
                        float* __restrict__ dinv) {
    int i = blockIdx.x * blockDim.x + threadIdx.x;
    if (i >= N_NODES) return;
    int rp = excl[i] + boff[i >> 8];
    rowptr[i] = rp;
    fill[i]   = rp;
    dinv[i]   = rsqrtf((float)degi[i] + 1.0f);
    if (i == 0) rowptr[N_NODES] = N_EDGES;
}

// ---- CSR fill: csr_src[pos] = src ----------------------------------------
__global__ void k_fill(const int* __restrict__ src, const int* __restrict__ dst,
                       int* __restrict__ fill, int* __restrict__ csr_src) {
    int e = blockIdx.x * blockDim.x + threadIdx.x;
    if (e >= N_EDGES) return;
    int d = dst[e];
    int pos = atomicAdd(&fill[d], 1);
    csr_src[pos] = src[e];
}

// ---- hs1 = ((x + po) @ W1) * dinv ----------------------------------------
__global__ void k_h1(const float* __restrict__ x, const float* __restrict__ W1,
                     const float* __restrict__ dinv, float* __restrict__ hs1) {
    __shared__ float sW[D_IN * D_H];
    __shared__ float spo[D_IN];
    for (int t = threadIdx.x; t < D_IN * D_H; t += blockDim.x) sW[t] = W1[t];
    if (threadIdx.x < D_IN) spo[threadIdx.x] = sinf((float)threadIdx.x);
    __syncthreads();
    int i = blockIdx.x * blockDim.x + threadIdx.x;
    if (i >= N_NODES) return;
    float xi[D_IN];
#pragma unroll
    for (int k = 0; k < D_IN; k++) xi[k] = x[i * D_IN + k] + spo[k];
    float di = dinv[i];
#pragma unroll
    for (int j = 0; j < D_H; j++) {
        float a = 0.f;
#pragma unroll
        for (int k = 0; k < D_IN; k++) a += xi[k] * sW[k * D_H + j];
        hs1[i * D_H + j] = a * di;
    }
}

// ---- GCN1 gather-aggregate + GELU + W2 matmul (fused) --------------------
// 5 threads per node (one float4 chunk each); block = 320 so quintets
// never straddle a block. LDS cross-lane reduce for the 20->5 matmul.
__global__ void k_agg1(const int* __restrict__ rowptr, const int* __restrict__ csr,
                       const float* __restrict__ hs1, const float* __restrict__ dinv,
                       const float* __restrict__ W2, const float* __restrict__ b1,
                       float* __restrict__ hs2) {
    __shared__ float sW[D_H * D_ENCC];   // 100
    __shared__ float sb[D_H];            // 20
    __shared__ float part[320][5];
    int tid = threadIdx.x;
    if (tid < D_H * D_ENCC) sW[tid] = W2[tid];
    if (tid >= 128 && tid < 128 + D_H) sb[tid - 128] = b1[tid - 128];
    int t = blockIdx.x * 320 + tid;
    bool act = t < N_NODES * 5;
    int i = act ? (t / 5) : 0;
    int c = act ? (t % 5) : 0;
    float4 acc = make_float4(0.f, 0.f, 0.f, 0.f);
    float di = 0.f;
    if (act) {
        acc = *(const float4*)(hs1 + (size_t)i * D_H + c * 4);  // self term
        int r0 = rowptr[i], r1 = rowptr[i + 1];
        for (int j = r0; j < r1; j++) {
            int s = csr[j];
            const float4 v = *(const float4*)(hs1 + (size_t)s * D_H + c * 4);
            acc.x += v.x; acc.y += v.y; acc.z += v.z; acc.w += v.w;
        }
        di = dinv[i];
    }
    __syncthreads();  // sW/sb ready; uniform point (loop lengths diverge but all arrive)
    float g0 = gelu_exact(di * acc.x + sb[c * 4 + 0]);
    float g1 = gelu_exact(di * acc.y + sb[c * 4 + 1]);
    float g2 = gelu_exact(di * acc.z + sb[c * 4 + 2]);
    float g3 = gelu_exact(di * acc.w + sb[c * 4 + 3]);
#pragma unroll
    for (int c2 = 0; c2 < 5; c2++) {
        part[tid][c2] = g0 * sW[(c * 4 + 0) * 5 + c2] + g1 * sW[(c * 4 + 1) * 5 + c2]
                      + g2 * sW[(c * 4 + 2) * 5 + c2] + g3 * sW[(c * 4 + 3) * 5 + c2];
    }
    __syncthreads();
    if (act) {
        int q = (tid / 5) * 5;
        float s = part[q][c] + part[q + 1][c] + part[q + 2][c]
                + part[q + 3][c] + part[q + 4][c];
        hs2[(size_t)i * 5 + c] = di * s;
    }
}

// ---- GCN2 gather-aggregate + GELU (fused) --------------------------------
__global__ void k_agg2(const int* __restrict__ rowptr, const int* __restrict__ csr,
                       const float* __restrict__ hs2, const float* __restrict__ dinv,
                       const float* __restrict__ b2, float* __restrict__ h2) {
    int t = blockIdx.x * blockDim.x + threadIdx.x;
    if (t >= N_NODES * 5) return;
    int i = t / 5;
    int c = t % 5;
    float acc = hs2[(size_t)i * 5 + c];  // self term
    int r0 = rowptr[i], r1 = rowptr[i + 1];
    for (int j = r0; j < r1; j++) {
        int s = csr[j];
        acc += hs2[(size_t)s * 5 + c];
    }
    h2[(size_t)i * 5 + c] = gelu_exact(dinv[i] * acc + b2[c]);
}

// ---- dense tail ----------------------------------------------------------
__global__ void k_dense(const float* __restrict__ h2,
                        const float* __restrict__ We, const float* __restrict__ be,
                        const float* __restrict__ Wd, const float* __restrict__ bd,
                        const float* __restrict__ Wr, const float* __restrict__ br,
                        float* __restrict__ out) {
    __shared__ float sWe[900], sWd[1800], sWr[210];
    __shared__ float sbe[30], sbd[60], sbr[7];
    for (int t = threadIdx.x; t < 900;  t += blockDim.x) sWe[t] = We[t];
    for (int t = threadIdx.x; t < 1800; t += blockDim.x) sWd[t] = Wd[t];
    for (int t = threadIdx.x; t < 210;  t += blockDim.x) sWr[t] = Wr[t];
    if (threadIdx.x < 30) sbe[threadIdx.x] = be[threadIdx.x];
    if (threadIdx.x >= 64  && threadIdx.x < 124) sbd[threadIdx.x - 64]  = bd[threadIdx.x - 64];
    if (threadIdx.x >= 128 && threadIdx.x < 135) sbr[threadIdx.x - 128] = br[threadIdx.x - 128];
    __syncthreads();
    int b = blockIdx.x * blockDim.x + threadIdx.x;
    if (b >= B_ROWS) return;

    float r[30];
#pragma unroll
    for (int k = 0; k < 30; k++) r[k] = h2[(size_t)b * 30 + k];

    float enc[30];
#pragma unroll
    for (int j = 0; j < 30; j++) {
        float a = sbe[j];
#pragma unroll
        for (int k = 0; k < 30; k++) a += r[k] * sWe[k * 30 + j];
        enc[j] = a;
    }

    float* x1o  = out;                        // [B,7]
    float* enco = out + (size_t)B_ROWS * 7;   // [B,30]
    float* outo = out + (size_t)B_ROWS * 37;  // [B,60]

#pragma unroll
    for (int j = 0; j < 30; j++) enco[(size_t)b * 30 + j] = enc[j];

#pragma unroll
    for (int k = 0; k < 30; k++) r[k] = gelu_exact(enc[k]);
#pragma unroll
    for (int j = 0; j < 60; j++) {
        float a = sbd[j];
#pragma unroll
        for (int k = 0; k < 30; k++) a += r[k] * sWd[k * 60 + j];
        outo[(size_t)b * 60 + j] = a;
    }
#pragma unroll
    for (int j = 0; j < 7; j++) {
        float a = sbr[j];
#pragma unroll
        for (int k = 0; k < 30; k++) a += enc[k] * sWr[k * 7 + j];
        x1o[(size_t)b * 7 + j] = a;
    }
}

extern "C" void kernel_launch(void* const* d_in, const int* in_sizes, int n_in,
                              void* d_out, int out_size, void* d_ws, size_t ws_size,
                              hipStream_t stream) {
    const float* x   = (const float*)d_in[0];
    const int*   ei  = (const int*)d_in[1];
    const int*   src = ei;
    const int*   dst = ei + N_EDGES;
    const float* W1  = (const float*)d_in[2];
    const float* b1  = (const float*)d_in[3];
    const float* W2  = (const float*)d_in[4];
    const float* b2  = (const float*)d_in[5];
    const float* We  = (const float*)d_in[6];
    const float* be  = (const float*)d_in[7];
    const float* Wd  = (const float*)d_in[8];
    const float* bd  = (const float*)d_in[9];
    const float* Wr  = (const float*)d_in[10];
    const float* br  = (const float*)d_in[11];

    char* ws = (char*)d_ws;
    int*   degi    = (int*)ws;                       ws += sizeof(int) * N_NODES;
    int*   excl    = (int*)ws;                       ws += sizeof(int) * N_NODES;
    int*   rowptr  = (int*)ws;                       ws += sizeof(int) * (N_NODES + 8);
    int*   fill    = (int*)ws;                       ws += sizeof(int) * N_NODES;
    int*   bsum    = (int*)ws;                       ws += sizeof(int) * (NB_SCAN + 8);
    int*   boff    = (int*)ws;                       ws += sizeof(int) * (NB_SCAN + 8);
    int*   csr_src = (int*)ws;                       ws += sizeof(int) * N_EDGES;
    float* dinv    = (float*)ws;                     ws += sizeof(float) * N_NODES;
    float* hs1     = (float*)ws;                     ws += sizeof(float) * (size_t)N_NODES * D_H;
    float* hs2     = (float*)ws;                     ws += sizeof(float) * (size_t)N_NODES * D_ENCC;
    float* h2      = (float*)ws;                     ws += sizeof(float) * (size_t)N_NODES * D_ENCC;

    hipMemsetAsync(degi, 0, sizeof(int) * N_NODES, stream);

    k_count<<<(N_EDGES + 255) / 256, 256, 0, stream>>>(dst, degi);
    k_scan1<<<NB_SCAN, 256, 0, stream>>>(degi, excl, bsum);
    k_scan2<<<1, 256, 0, stream>>>(bsum, boff);
    k_scan3<<<NB_SCAN, 256, 0, stream>>>(excl, boff, degi, rowptr, fill, dinv);
    k_h1  <<<(N_NODES + 255) / 256, 256, 0, stream>>>(x, W1, dinv, hs1);
    k_fill<<<(N_EDGES + 255) / 256, 256, 0, stream>>>(src, dst, fill, csr_src);
    k_agg1<<<(N_NODES * 5 + 319) / 320, 320, 0, stream>>>(rowptr, csr_src, hs1, dinv,
                                                          W2, b1, hs2);
    k_agg2<<<(N_NODES * 5 + 255) / 256, 256, 0, stream>>>(rowptr, csr_src, hs2, dinv,
                                                          b2, h2);
    k_dense<<<(B_ROWS + 255) / 256, 256, 0, stream>>>(h2, We, be, Wd, bd, Wr, br,
                                                      (float*)d_out);
}

// Round 3
// 1211.884 us; speedup vs baseline: 7.2697x; 1.7005x over previous
//
#include <hip/hip_runtime.h>
#include <math.h>

#define N_NODES 1200000
#define N_EDGES 12000000
#define D_IN    10
#define D_H     20
#define D_ENCC  5
#define VECC    6
#define B_ROWS  200000

#define NBUCK   2048
#define BNODES  586                              // ceil(N_NODES / NBUCK)
#define EPB     16384                            // edges per block in edge passes
#define NBLK_E  ((N_EDGES + EPB - 1) / EPB)      // 733
#define CAP     8192                             // LDS CSR staging capacity (mean 5860, +30 sigma)

__device__ __forceinline__ float gelu_exact(float x) {
    return 0.5f * x * (1.0f + erff(x * 0.70710678118654752f));
}

// ---- pass 1: coarse bucket histogram (LDS-aggregated) --------------------
__global__ void k_bhist(const int* __restrict__ dst, int* __restrict__ gcount) {
    __shared__ int h[NBUCK];
    for (int t = threadIdx.x; t < NBUCK; t += 256) h[t] = 0;
    __syncthreads();
    long e0 = (long)blockIdx.x * EPB;
    for (int k = 0; k < EPB / 256; k++) {
        long e = e0 + threadIdx.x + k * 256;
        if (e < N_EDGES) atomicAdd(&h[dst[e] / BNODES], 1);
    }
    __syncthreads();
    for (int t = threadIdx.x; t < NBUCK; t += 256)
        if (h[t]) atomicAdd(&gcount[t], h[t]);
}

// ---- pass 2: scan bucket counts (single block) ---------------------------
__global__ void k_bscan(const int* __restrict__ gcount, int* __restrict__ bstart,
                        int* __restrict__ bcursor) {
    __shared__ int ls[NBUCK];
    __shared__ int ps[256];
    int tid = threadIdx.x;
    for (int t = tid; t < NBUCK; t += 256) ls[t] = gcount[t];
    __syncthreads();
    int s = 0;
#pragma unroll
    for (int k = 0; k < NBUCK / 256; k++) s += ls[tid * (NBUCK / 256) + k];
    ps[tid] = s;
    __syncthreads();
    for (int off = 1; off < 256; off <<= 1) {
        int v = (tid >= off) ? ps[tid - off] : 0;
        __syncthreads();
        ps[tid] += v;
        __syncthreads();
    }
    int run = ps[tid] - s;
#pragma unroll
    for (int k = 0; k < NBUCK / 256; k++) {
        int idx = tid * (NBUCK / 256) + k;
        int c = ls[idx];
        bstart[idx] = run;
        bcursor[idx] = run;
        run += c;
    }
    if (tid == 255) bstart[NBUCK] = N_EDGES;
}

// ---- pass 3: scatter packed (dst,src) records into buckets ---------------
__global__ void k_bscatter(const int* __restrict__ src, const int* __restrict__ dst,
                           int* __restrict__ bcursor,
                           unsigned long long* __restrict__ upack) {
    __shared__ int h[NBUCK];
    __shared__ int base[NBUCK];
    for (int t = threadIdx.x; t < NBUCK; t += 256) h[t] = 0;
    __syncthreads();
    long e0 = (long)blockIdx.x * EPB;
    for (int k = 0; k < EPB / 256; k++) {
        long e = e0 + threadIdx.x + k * 256;
        if (e < N_EDGES) atomicAdd(&h[dst[e] / BNODES], 1);
    }
    __syncthreads();
    for (int t = threadIdx.x; t < NBUCK; t += 256) {
        int c = h[t];
        base[t] = c ? atomicAdd(&bcursor[t], c) : 0;
        h[t] = 0;
    }
    __syncthreads();
    for (int k = 0; k < EPB / 256; k++) {
        long e = e0 + threadIdx.x + k * 256;
        if (e < N_EDGES) {
            int d = dst[e], s = src[e];
            int b = d / BNODES;
            int r = atomicAdd(&h[b], 1);
            upack[(size_t)base[b] + r] =
                ((unsigned long long)(unsigned int)d << 32) | (unsigned int)s;
        }
    }
}

// ---- pass 4: per-bucket CSR build entirely in LDS ------------------------
__global__ void k_bbuild(const unsigned long long* __restrict__ upack,
                         const int* __restrict__ bstart,
                         int* __restrict__ csr, int* __restrict__ rowptr,
                         float* __restrict__ dinv) {
    __shared__ int sdeg[BNODES];
    __shared__ int scur[BNODES];
    __shared__ int ps[256];
    __shared__ int stage[CAP];
    int b = blockIdx.x, tid = threadIdx.x;
    int n0 = b * BNODES;
    int n1 = n0 + BNODES; if (n1 > N_NODES) n1 = N_NODES;
    int nn = n1 - n0;
    int e0 = bstart[b], e1 = bstart[b + 1];
    int cnt = e1 - e0;
    for (int t = tid; t < nn; t += 256) sdeg[t] = 0;
    __syncthreads();
    for (int p = tid; p < cnt; p += 256) {
        int d = (int)(upack[e0 + p] >> 32);
        atomicAdd(&sdeg[d - n0], 1);
    }
    __syncthreads();
    // exclusive scan over nn (<=586) degrees, 3 elements / thread
    int i0 = tid * 3;
    int s = 0;
#pragma unroll
    for (int k = 0; k < 3; k++) { int i = i0 + k; if (i < nn) s += sdeg[i]; }
    ps[tid] = s;
    __syncthreads();
    for (int off = 1; off < 256; off <<= 1) {
        int v = (tid >= off) ? ps[tid - off] : 0;
        __syncthreads();
        ps[tid] += v;
        __syncthreads();
    }
    int run = ps[tid] - s;
#pragma unroll
    for (int k = 0; k < 3; k++) {
        int i = i0 + k;
        if (i < nn) {
            int dg = sdeg[i];
            scur[i] = run;
            rowptr[n0 + i] = e0 + run;
            dinv[n0 + i] = rsqrtf((float)dg + 1.0f);
            run += dg;
        }
    }
    if (b == 0 && tid == 0) rowptr[N_NODES] = N_EDGES;
    __syncthreads();
    for (int p = tid; p < cnt; p += 256) {
        unsigned long long u = upack[e0 + p];
        int d = (int)(u >> 32);
        int sv = (int)(u & 0xffffffffull);
        int r = atomicAdd(&scur[d - n0], 1);
        if (r < CAP) stage[r] = sv;
        else         csr[e0 + r] = sv;   // overflow fallback (statistically never)
    }
    __syncthreads();
    int lim = cnt < CAP ? cnt : CAP;
    for (int p = tid; p < lim; p += 256) csr[e0 + p] = stage[p];
}

// ---- hs1 = ((x + po) @ W1) * dinv ----------------------------------------
__global__ void k_h1(const float* __restrict__ x, const float* __restrict__ W1,
                     const float* __restrict__ dinv, float* __restrict__ hs1) {
    __shared__ float sW[D_IN * D_H];
    __shared__ float spo[D_IN];
    for (int t = threadIdx.x; t < D_IN * D_H; t += blockDim.x) sW[t] = W1[t];
    if (threadIdx.x < D_IN) spo[threadIdx.x] = sinf((float)threadIdx.x);
    __syncthreads();
    int i = blockIdx.x * blockDim.x + threadIdx.x;
    if (i >= N_NODES) return;
    float xi[D_IN];
#pragma unroll
    for (int k = 0; k < D_IN; k++) xi[k] = x[i * D_IN + k] + spo[k];
    float di = dinv[i];
#pragma unroll
    for (int j = 0; j < D_H; j++) {
        float a = 0.f;
#pragma unroll
        for (int k = 0; k < D_IN; k++) a += xi[k] * sW[k * D_H + j];
        hs1[i * D_H + j] = a * di;
    }
}

// ---- GCN1 gather-aggregate + GELU + W2 matmul (fused) --------------------
__global__ void k_agg1(const int* __restrict__ rowptr, const int* __restrict__ csr,
                       const float* __restrict__ hs1, const float* __restrict__ dinv,
                       const float* __restrict__ W2, const float* __restrict__ b1,
                       float* __restrict__ hs2) {
    __shared__ float sW[D_H * D_ENCC];
    __shared__ float sb[D_H];
    __shared__ float part[320][5];
    int tid = threadIdx.x;
    if (tid < D_H * D_ENCC) sW[tid] = W2[tid];
    if (tid >= 128 && tid < 128 + D_H) sb[tid - 128] = b1[tid - 128];
    int t = blockIdx.x * 320 + tid;
    bool act = t < N_NODES * 5;
    int i = act ? (t / 5) : 0;
    int c = act ? (t % 5) : 0;
    float4 acc = make_float4(0.f, 0.f, 0.f, 0.f);
    float di = 0.f;
    if (act) {
        acc = *(const float4*)(hs1 + (size_t)i * D_H + c * 4);  // self term
        int r0 = rowptr[i], r1 = rowptr[i + 1];
        for (int j = r0; j < r1; j++) {
            int s = csr[j];
            const float4 v = *(const float4*)(hs1 + (size_t)s * D_H + c * 4);
            acc.x += v.x; acc.y += v.y; acc.z += v.z; acc.w += v.w;
        }
        di = dinv[i];
    }
    __syncthreads();
    float g0 = gelu_exact(di * acc.x + sb[c * 4 + 0]);
    float g1 = gelu_exact(di * acc.y + sb[c * 4 + 1]);
    float g2 = gelu_exact(di * acc.z + sb[c * 4 + 2]);
    float g3 = gelu_exact(di * acc.w + sb[c * 4 + 3]);
#pragma unroll
    for (int c2 = 0; c2 < 5; c2++) {
        part[tid][c2] = g0 * sW[(c * 4 + 0) * 5 + c2] + g1 * sW[(c * 4 + 1) * 5 + c2]
                      + g2 * sW[(c * 4 + 2) * 5 + c2] + g3 * sW[(c * 4 + 3) * 5 + c2];
    }
    __syncthreads();
    if (act) {
        int q = (tid / 5) * 5;
        float s = part[q][c] + part[q + 1][c] + part[q + 2][c]
                + part[q + 3][c] + part[q + 4][c];
        hs2[(size_t)i * 5 + c] = di * s;
    }
}

// ---- GCN2 gather-aggregate + GELU (fused) --------------------------------
__global__ void k_agg2(const int* __restrict__ rowptr, const int* __restrict__ csr,
                       const float* __restrict__ hs2, const float* __restrict__ dinv,
                       const float* __restrict__ b2, float* __restrict__ h2) {
    int t = blockIdx.x * blockDim.x + threadIdx.x;
    if (t >= N_NODES * 5) return;
    int i = t / 5;
    int c = t % 5;
    float acc = hs2[(size_t)i * 5 + c];
    int r0 = rowptr[i], r1 = rowptr[i + 1];
    for (int j = r0; j < r1; j++) {
        int s = csr[j];
        acc += hs2[(size_t)s * 5 + c];
    }
    h2[(size_t)i * 5 + c] = gelu_exact(dinv[i] * acc + b2[c]);
}

// ---- dense tail ----------------------------------------------------------
__global__ void k_dense(const float* __restrict__ h2,
                        const float* __restrict__ We, const float* __restrict__ be,
                        const float* __restrict__ Wd, const float* __restrict__ bd,
                        const float* __restrict__ Wr, const float* __restrict__ br,
                        float* __restrict__ out) {
    __shared__ float sWe[900], sWd[1800], sWr[210];
    __shared__ float sbe[30], sbd[60], sbr[7];
    for (int t = threadIdx.x; t < 900;  t += blockDim.x) sWe[t] = We[t];
    for (int t = threadIdx.x; t < 1800; t += blockDim.x) sWd[t] = Wd[t];
    for (int t = threadIdx.x; t < 210;  t += blockDim.x) sWr[t] = Wr[t];
    if (threadIdx.x < 30) sbe[threadIdx.x] = be[threadIdx.x];
    if (threadIdx.x >= 64  && threadIdx.x < 124) sbd[threadIdx.x - 64]  = bd[threadIdx.x - 64];
    if (threadIdx.x >= 128 && threadIdx.x < 135) sbr[threadIdx.x - 128] = br[threadIdx.x - 128];
    __syncthreads();
    int b = blockIdx.x * blockDim.x + threadIdx.x;
    if (b >= B_ROWS) return;

    float r[30];
#pragma unroll
    for (int k = 0; k < 30; k++) r[k] = h2[(size_t)b * 30 + k];

    float enc[30];
#pragma unroll
    for (int j = 0; j < 30; j++) {
        float a = sbe[j];
#pragma unroll
        for (int k = 0; k < 30; k++) a += r[k] * sWe[k * 30 + j];
        enc[j] = a;
    }

    float* x1o  = out;                        // [B,7]
    float* enco = out + (size_t)B_ROWS * 7;   // [B,30]
    float* outo = out + (size_t)B_ROWS * 37;  // [B,60]

#pragma unroll
    for (int j = 0; j < 30; j++) enco[(size_t)b * 30 + j] = enc[j];

#pragma unroll
    for (int k = 0; k < 30; k++) r[k] = gelu_exact(enc[k]);
#pragma unroll
    for (int j = 0; j < 60; j++) {
        float a = sbd[j];
#pragma unroll
        for (int k = 0; k < 30; k++) a += r[k] * sWd[k * 60 + j];
        outo[(size_t)b * 60 + j] = a;
    }
#pragma unroll
    for (int j = 0; j < 7; j++) {
        float a = sbr[j];
#pragma unroll
        for (int k = 0; k < 30; k++) a += enc[k] * sWr[k * 7 + j];
        x1o[(size_t)b * 7 + j] = a;
    }
}

extern "C" void kernel_launch(void* const* d_in, const int* in_sizes, int n_in,
                              void* d_out, int out_size, void* d_ws, size_t ws_size,
                              hipStream_t stream) {
    const float* x   = (const float*)d_in[0];
    const int*   ei  = (const int*)d_in[1];
    const int*   src = ei;
    const int*   dst = ei + N_EDGES;
    const float* W1  = (const float*)d_in[2];
    const float* b1  = (const float*)d_in[3];
    const float* W2  = (const float*)d_in[4];
    const float* b2  = (const float*)d_in[5];
    const float* We  = (const float*)d_in[6];
    const float* be  = (const float*)d_in[7];
    const float* Wd  = (const float*)d_in[8];
    const float* bd  = (const float*)d_in[9];
    const float* Wr  = (const float*)d_in[10];
    const float* br  = (const float*)d_in[11];

    char* ws = (char*)d_ws;
    // upack (96 MB) is later reused as hs1 (96 MB) — k_bbuild finishes before k_h1 writes.
    unsigned long long* upack = (unsigned long long*)ws;  ws += sizeof(unsigned long long) * (size_t)N_EDGES;
    float* hs1    = (float*)upack;
    int*   csr    = (int*)ws;       ws += sizeof(int) * (size_t)N_EDGES;
    int*   rowptr = (int*)ws;       ws += sizeof(int) * (N_NODES + 8);
    float* dinv   = (float*)ws;     ws += sizeof(float) * N_NODES;
    float* hs2    = (float*)ws;     ws += sizeof(float) * (size_t)N_NODES * D_ENCC;
    float* h2     = (float*)ws;     ws += sizeof(float) * (size_t)N_NODES * D_ENCC;
    int*   gcount = (int*)ws;       ws += sizeof(int) * NBUCK;
    int*   bstart = (int*)ws;       ws += sizeof(int) * (NBUCK + 8);
    int*   bcursor= (int*)ws;       ws += sizeof(int) * NBUCK;

    hipMemsetAsync(gcount, 0, sizeof(int) * NBUCK, stream);

    k_bhist   <<<NBLK_E, 256, 0, stream>>>(dst, gcount);
    k_bscan   <<<1, 256, 0, stream>>>(gcount, bstart, bcursor);
    k_bscatter<<<NBLK_E, 256, 0, stream>>>(src, dst, bcursor, upack);
    k_bbuild  <<<NBUCK, 256, 0, stream>>>(upack, bstart, csr, rowptr, dinv);
    k_h1      <<<(N_NODES + 255) / 256, 256, 0, stream>>>(x, W1, dinv, hs1);
    k_agg1    <<<(N_NODES * 5 + 319) / 320, 320, 0, stream>>>(rowptr, csr, hs1, dinv,
                                                              W2, b1, hs2);
    k_agg2    <<<(N_NODES * 5 + 255) / 256, 256, 0, stream>>>(rowptr, csr, hs2, dinv,
                                                              b2, h2);
    k_dense   <<<(B_ROWS + 255) / 256, 256, 0, stream>>>(h2, We, be, Wd, bd, Wr, br,
                                                         (float*)d_out);
}

// Round 4
// 1127.154 us; speedup vs baseline: 7.8162x; 1.0752x over previous
//
#include <hip/hip_runtime.h>
#include <math.h>

#define N_NODES 1200000
#define N_EDGES 12000000
#define D_IN    10
#define D_H     20
#define D_ENCC  5
#define VECC    6
#define B_ROWS  200000

#define NBUCK   2048
#define BNODES  586                              // ceil(N_NODES / NBUCK)
#define EPB     16384                            // edges per block in edge passes
#define NBLK_E  ((N_EDGES + EPB - 1) / EPB)      // 733
#define CAP     8192                             // LDS CSR staging capacity
#define PADX    16                               // xs row = 16 floats (64 B, 1 sector)
#define PADH    8                                // hs2 row = 8 floats (32 B)

__device__ __forceinline__ float gelu_exact(float x) {
    return 0.5f * x * (1.0f + erff(x * 0.70710678118654752f));
}

// ---- pass 1: coarse bucket histogram (LDS-aggregated) --------------------
__global__ void k_bhist(const int* __restrict__ dst, int* __restrict__ gcount) {
    __shared__ int h[NBUCK];
    for (int t = threadIdx.x; t < NBUCK; t += 256) h[t] = 0;
    __syncthreads();
    long e0 = (long)blockIdx.x * EPB;
    for (int k = 0; k < EPB / 256; k++) {
        long e = e0 + threadIdx.x + k * 256;
        if (e < N_EDGES) atomicAdd(&h[dst[e] / BNODES], 1);
    }
    __syncthreads();
    for (int t = threadIdx.x; t < NBUCK; t += 256)
        if (h[t]) atomicAdd(&gcount[t], h[t]);
}

// ---- pass 2: scan bucket counts (single block) ---------------------------
__global__ void k_bscan(const int* __restrict__ gcount, int* __restrict__ bstart,
                        int* __restrict__ bcursor) {
    __shared__ int ls[NBUCK];
    __shared__ int ps[256];
    int tid = threadIdx.x;
    for (int t = tid; t < NBUCK; t += 256) ls[t] = gcount[t];
    __syncthreads();
    int s = 0;
#pragma unroll
    for (int k = 0; k < NBUCK / 256; k++) s += ls[tid * (NBUCK / 256) + k];
    ps[tid] = s;
    __syncthreads();
    for (int off = 1; off < 256; off <<= 1) {
        int v = (tid >= off) ? ps[tid - off] : 0;
        __syncthreads();
        ps[tid] += v;
        __syncthreads();
    }
    int run = ps[tid] - s;
#pragma unroll
    for (int k = 0; k < NBUCK / 256; k++) {
        int idx = tid * (NBUCK / 256) + k;
        int c = ls[idx];
        bstart[idx] = run;
        bcursor[idx] = run;
        run += c;
    }
    if (tid == 255) bstart[NBUCK] = N_EDGES;
}

// ---- pass 3: scatter packed 4B (local_dst<<21 | src) records -------------
__global__ void k_bscatter(const int* __restrict__ src, const int* __restrict__ dst,
                           int* __restrict__ bcursor, unsigned int* __restrict__ epack) {
    __shared__ int h[NBUCK];
    __shared__ int base[NBUCK];
    for (int t = threadIdx.x; t < NBUCK; t += 256) h[t] = 0;
    __syncthreads();
    long e0 = (long)blockIdx.x * EPB;
    for (int k = 0; k < EPB / 256; k++) {
        long e = e0 + threadIdx.x + k * 256;
        if (e < N_EDGES) atomicAdd(&h[dst[e] / BNODES], 1);
    }
    __syncthreads();
    for (int t = threadIdx.x; t < NBUCK; t += 256) {
        int c = h[t];
        base[t] = c ? atomicAdd(&bcursor[t], c) : 0;
        h[t] = 0;
    }
    __syncthreads();
    for (int k = 0; k < EPB / 256; k++) {
        long e = e0 + threadIdx.x + k * 256;
        if (e < N_EDGES) {
            int d = dst[e], s = src[e];
            int b = d / BNODES;
            int r = atomicAdd(&h[b], 1);
            epack[(size_t)base[b] + r] =
                ((unsigned int)(d - b * BNODES) << 21) | (unsigned int)s;
        }
    }
}

// ---- pass 4: per-bucket CSR build in LDS + dinv + xs = (x+po)*dinv -------
__global__ void k_bbuild(const unsigned int* __restrict__ epack,
                         const int* __restrict__ bstart,
                         const float* __restrict__ x,
                         int* __restrict__ csr, int* __restrict__ rowptr,
                         float* __restrict__ dinv, float* __restrict__ xs) {
    __shared__ int sdeg[BNODES];
    __shared__ int scur[BNODES];
    __shared__ int ps[256];
    __shared__ int stage[CAP];
    __shared__ float spo[D_IN];
    int b = blockIdx.x, tid = threadIdx.x;
    if (tid < D_IN) spo[tid] = sinf((float)tid);
    int n0 = b * BNODES;
    int n1 = n0 + BNODES; if (n1 > N_NODES) n1 = N_NODES;
    int nn = n1 - n0;
    int e0 = bstart[b], e1 = bstart[b + 1];
    int cnt = e1 - e0;
    for (int t = tid; t < nn; t += 256) sdeg[t] = 0;
    __syncthreads();
    for (int p = tid; p < cnt; p += 256)
        atomicAdd(&sdeg[epack[e0 + p] >> 21], 1);
    __syncthreads();
    // exclusive scan over nn (<=586) degrees, 3 elements / thread
    int i0 = tid * 3;
    int s = 0;
#pragma unroll
    for (int k = 0; k < 3; k++) { int i = i0 + k; if (i < nn) s += sdeg[i]; }
    ps[tid] = s;
    __syncthreads();
    for (int off = 1; off < 256; off <<= 1) {
        int v = (tid >= off) ? ps[tid - off] : 0;
        __syncthreads();
        ps[tid] += v;
        __syncthreads();
    }
    int run = ps[tid] - s;
#pragma unroll
    for (int k = 0; k < 3; k++) {
        int i = i0 + k;
        if (i < nn) {
            int dg = sdeg[i];
            scur[i] = run;
            rowptr[n0 + i] = e0 + run;
            dinv[n0 + i] = rsqrtf((float)dg + 1.0f);
            run += dg;
        }
    }
    if (b == 0 && tid == 0) rowptr[N_NODES] = N_EDGES;
    __syncthreads();
    for (int p = tid; p < cnt; p += 256) {
        unsigned int u = epack[e0 + p];
        int dl = u >> 21;
        int sv = (int)(u & 0x1FFFFFu);
        int r = atomicAdd(&scur[dl], 1);
        if (r < CAP) stage[r] = sv;
        else         csr[e0 + r] = sv;   // overflow fallback (statistically never)
    }
    __syncthreads();
    int lim = cnt < CAP ? cnt : CAP;
    for (int p = tid; p < lim; p += 256) csr[e0 + p] = stage[p];
    // xs rows (padded to 16 floats): sdeg still intact
    for (int p = tid; p < nn * PADX; p += 256) {
        int ln = p >> 4;
        int k  = p & 15;
        float v = 0.f;
        if (k < D_IN)
            v = (x[(size_t)(n0 + ln) * D_IN + k] + spo[k]) *
                rsqrtf((float)sdeg[ln] + 1.0f);
        xs[(size_t)(n0 + ln) * PADX + k] = v;
    }
}

// ---- GCN1: aggregate 10-dim xs, then fused W1+b1 -> gelu -> W2 -> *dinv --
__global__ void k_agg1(const int* __restrict__ rowptr, const int* __restrict__ csr,
                       const float* __restrict__ xs, const float* __restrict__ dinv,
                       const float* __restrict__ W1, const float* __restrict__ b1,
                       const float* __restrict__ W2, float* __restrict__ hs2p) {
    __shared__ float sW1[D_IN * D_H];   // 200
    __shared__ float sb1[D_H];          // 20
    __shared__ float sW2[D_H * D_ENCC]; // 100
    __shared__ float sy[64][10];
    __shared__ float part[320][5];
    int tid = threadIdx.x;
    if      (tid < 200) sW1[tid] = W1[tid];
    else if (tid < 220) sb1[tid - 200] = b1[tid - 200];
    else                sW2[tid - 220] = W2[tid - 220];
    long t = (long)blockIdx.x * 320 + tid;
    bool act = t < (long)N_NODES * 5;   // grid exact: always true, kept for safety
    int i = (int)(t / 5);
    int c = tid % 5;
    int ln = tid / 5;                   // 0..63
    float2 acc = make_float2(0.f, 0.f);
    float di = 0.f;
    if (act) {
        acc = *(const float2*)(xs + (size_t)i * PADX + c * 2);  // self term
        int r0 = rowptr[i], r1 = rowptr[i + 1];
        for (int j = r0; j < r1; j++) {
            int s = csr[j];
            const float2 v = *(const float2*)(xs + (size_t)s * PADX + c * 2);
            acc.x += v.x; acc.y += v.y;
        }
        di = dinv[i];
    }
    __syncthreads();   // weights ready; all lanes arrive
    sy[ln][c * 2]     = di * acc.x;
    sy[ln][c * 2 + 1] = di * acc.y;
    __syncthreads();
    float y[10];
#pragma unroll
    for (int k = 0; k < 10; k++) y[k] = sy[ln][k];
    float p0 = 0.f, p1 = 0.f, p2 = 0.f, p3 = 0.f, p4 = 0.f;
#pragma unroll
    for (int jj = 0; jj < 4; jj++) {
        int j = c * 4 + jj;
        float tv = sb1[j];
#pragma unroll
        for (int k = 0; k < 10; k++) tv += y[k] * sW1[k * D_H + j];
        float g = gelu_exact(tv);
        p0 += g * sW2[j * 5 + 0]; p1 += g * sW2[j * 5 + 1]; p2 += g * sW2[j * 5 + 2];
        p3 += g * sW2[j * 5 + 3]; p4 += g * sW2[j * 5 + 4];
    }
    part[tid][0] = p0; part[tid][1] = p1; part[tid][2] = p2;
    part[tid][3] = p3; part[tid][4] = p4;
    __syncthreads();
    if (act) {
        int q = ln * 5;
        float sm = part[q][c] + part[q + 1][c] + part[q + 2][c]
                 + part[q + 3][c] + part[q + 4][c];
        hs2p[(size_t)i * PADH + c] = di * sm;
    }
}

// ---- GCN2 gather-aggregate + GELU (32B-padded rows) ----------------------
__global__ void k_agg2(const int* __restrict__ rowptr, const int* __restrict__ csr,
                       const float* __restrict__ hs2p, const float* __restrict__ dinv,
                       const float* __restrict__ b2, float* __restrict__ h2) {
    long t = (long)blockIdx.x * blockDim.x + threadIdx.x;
    if (t >= (long)N_NODES * 5) return;
    int i = (int)(t / 5);
    int c = (int)(t % 5);
    float acc = hs2p[(size_t)i * PADH + c];   // self term
    int r0 = rowptr[i], r1 = rowptr[i + 1];
    for (int j = r0; j < r1; j++)
        acc += hs2p[(size_t)csr[j] * PADH + c];
    h2[(size_t)i * 5 + c] = gelu_exact(dinv[i] * acc + b2[c]);
}

// ---- dense tail ----------------------------------------------------------
__global__ void k_dense(const float* __restrict__ h2,
                        const float* __restrict__ We, const float* __restrict__ be,
                        const float* __restrict__ Wd, const float* __restrict__ bd,
                        const float* __restrict__ Wr, const float* __restrict__ br,
                        float* __restrict__ out) {
    __shared__ float sWe[900], sWd[1800], sWr[210];
    __shared__ float sbe[30], sbd[60], sbr[7];
    for (int t = threadIdx.x; t < 900;  t += blockDim.x) sWe[t] = We[t];
    for (int t = threadIdx.x; t < 1800; t += blockDim.x) sWd[t] = Wd[t];
    for (int t = threadIdx.x; t < 210;  t += blockDim.x) sWr[t] = Wr[t];
    if (threadIdx.x < 30) sbe[threadIdx.x] = be[threadIdx.x];
    if (threadIdx.x >= 64  && threadIdx.x < 124) sbd[threadIdx.x - 64]  = bd[threadIdx.x - 64];
    if (threadIdx.x >= 128 && threadIdx.x < 135) sbr[threadIdx.x - 128] = br[threadIdx.x - 128];
    __syncthreads();
    int b = blockIdx.x * blockDim.x + threadIdx.x;
    if (b >= B_ROWS) return;

    float r[30];
#pragma unroll
    for (int k = 0; k < 30; k++) r[k] = h2[(size_t)b * 30 + k];

    float enc[30];
#pragma unroll
    for (int j = 0; j < 30; j++) {
        float a = sbe[j];
#pragma unroll
        for (int k = 0; k < 30; k++) a += r[k] * sWe[k * 30 + j];
        enc[j] = a;
    }

    float* x1o  = out;                        // [B,7]
    float* enco = out + (size_t)B_ROWS * 7;   // [B,30]
    float* outo = out + (size_t)B_ROWS * 37;  // [B,60]

#pragma unroll
    for (int j = 0; j < 30; j++) enco[(size_t)b * 30 + j] = enc[j];

#pragma unroll
    for (int k = 0; k < 30; k++) r[k] = gelu_exact(enc[k]);
#pragma unroll
    for (int j = 0; j < 60; j++) {
        float a = sbd[j];
#pragma unroll
        for (int k = 0; k < 30; k++) a += r[k] * sWd[k * 60 + j];
        outo[(size_t)b * 60 + j] = a;
    }
#pragma unroll
    for (int j = 0; j < 7; j++) {
        float a = sbr[j];
#pragma unroll
        for (int k = 0; k < 30; k++) a += enc[k] * sWr[k * 7 + j];
        x1o[(size_t)b * 7 + j] = a;
    }
}

extern "C" void kernel_launch(void* const* d_in, const int* in_sizes, int n_in,
                              void* d_out, int out_size, void* d_ws, size_t ws_size,
                              hipStream_t stream) {
    const float* x   = (const float*)d_in[0];
    const int*   ei  = (const int*)d_in[1];
    const int*   src = ei;
    const int*   dst = ei + N_EDGES;
    const float* W1  = (const float*)d_in[2];
    const float* b1  = (const float*)d_in[3];
    const float* W2  = (const float*)d_in[4];
    const float* b2  = (const float*)d_in[5];
    const float* We  = (const float*)d_in[6];
    const float* be  = (const float*)d_in[7];
    const float* Wd  = (const float*)d_in[8];
    const float* bd  = (const float*)d_in[9];
    const float* Wr  = (const float*)d_in[10];
    const float* br  = (const float*)d_in[11];

    char* ws = (char*)d_ws;
    // epack (48 MB) is consumed by k_bbuild, then reused as hs2p (38.4 MB).
    unsigned int* epack = (unsigned int*)ws;  ws += sizeof(unsigned int) * (size_t)N_EDGES;
    float* hs2p  = (float*)epack;
    int*   csr    = (int*)ws;   ws += sizeof(int) * (size_t)N_EDGES;
    int*   rowptr = (int*)ws;   ws += sizeof(int) * (N_NODES + 16);
    float* dinv   = (float*)ws; ws += sizeof(float) * N_NODES;
    float* xs     = (float*)ws; ws += sizeof(float) * (size_t)N_NODES * PADX;
    float* h2     = (float*)ws; ws += sizeof(float) * (size_t)N_NODES * D_ENCC;
    int*   gcount = (int*)ws;   ws += sizeof(int) * NBUCK;
    int*   bstart = (int*)ws;   ws += sizeof(int) * (NBUCK + 16);
    int*   bcursor= (int*)ws;   ws += sizeof(int) * NBUCK;

    hipMemsetAsync(gcount, 0, sizeof(int) * NBUCK, stream);

    k_bhist   <<<NBLK_E, 256, 0, stream>>>(dst, gcount);
    k_bscan   <<<1, 256, 0, stream>>>(gcount, bstart, bcursor);
    k_bscatter<<<NBLK_E, 256, 0, stream>>>(src, dst, bcursor, epack);
    k_bbuild  <<<NBUCK, 256, 0, stream>>>(epack, bstart, x, csr, rowptr, dinv, xs);
    k_agg1    <<<(int)(((long)N_NODES * 5) / 320), 320, 0, stream>>>(rowptr, csr, xs,
                                                                     dinv, W1, b1, W2, hs2p);
    k_agg2    <<<(int)(((long)N_NODES * 5 + 255) / 256), 256, 0, stream>>>(rowptr, csr,
                                                                           hs2p, dinv, b2, h2);
    k_dense   <<<(B_ROWS + 255) / 256, 256, 0, stream>>>(h2, We, be, Wd, bd, Wr, br,
                                                         (float*)d_out);
}

// Round 5
// 969.961 us; speedup vs baseline: 9.0829x; 1.1621x over previous
//
#include <hip/hip_runtime.h>
#include <math.h>

#define N_NODES 1200000
#define N_EDGES 12000000
#define D_IN    10
#define D_H     20
#define D_ENCC  5
#define VECC    6
#define B_ROWS  200000

#define NBUCK   2048
#define BNODES  586                              // ceil(N_NODES / NBUCK)
#define EPB     16384                            // edges per tile
#define NBLK_E  ((N_EDGES + EPB - 1) / EPB)      // 733
#define CAP     8192                             // LDS CSR staging capacity
#define PADX    16                               // xs row = 16 floats (64 B, 1 sector)
#define PADH    8                                // hs2 row = 8 floats (32 B)

__device__ __forceinline__ float gelu_exact(float x) {
    return 0.5f * x * (1.0f + erff(x * 0.70710678118654752f));
}

// ---- pass 1: coarse bucket histogram + per-tile hist row -----------------
__global__ void k_bhist(const int* __restrict__ dst, int* __restrict__ gcount,
                        int* __restrict__ hist) {
    __shared__ int h[NBUCK];
    for (int t = threadIdx.x; t < NBUCK; t += 256) h[t] = 0;
    __syncthreads();
    long e0 = (long)blockIdx.x * EPB;
    for (int k = 0; k < EPB / 256; k++) {
        long e = e0 + threadIdx.x + k * 256;
        if (e < N_EDGES) atomicAdd(&h[dst[e] / BNODES], 1);
    }
    __syncthreads();
    size_t row = (size_t)blockIdx.x * NBUCK;
    for (int t = threadIdx.x; t < NBUCK; t += 256) {
        int c = h[t];
        hist[row + t] = c;
        if (c) atomicAdd(&gcount[t], c);
    }
}

// ---- pass 2: scan bucket counts (single block) ---------------------------
__global__ void k_bscan(const int* __restrict__ gcount, int* __restrict__ bstart,
                        int* __restrict__ bcursor) {
    __shared__ int ls[NBUCK];
    __shared__ int ps[256];
    int tid = threadIdx.x;
    for (int t = tid; t < NBUCK; t += 256) ls[t] = gcount[t];
    __syncthreads();
    int s = 0;
#pragma unroll
    for (int k = 0; k < NBUCK / 256; k++) s += ls[tid * (NBUCK / 256) + k];
    ps[tid] = s;
    __syncthreads();
    for (int off = 1; off < 256; off <<= 1) {
        int v = (tid >= off) ? ps[tid - off] : 0;
        __syncthreads();
        ps[tid] += v;
        __syncthreads();
    }
    int run = ps[tid] - s;
#pragma unroll
    for (int k = 0; k < NBUCK / 256; k++) {
        int idx = tid * (NBUCK / 256) + k;
        int c = ls[idx];
        bstart[idx] = run;
        bcursor[idx] = run;
        run += c;
    }
    if (tid == 255) bstart[NBUCK] = N_EDGES;
}

// ---- pass 3: tile-sort scatter — coalesced bucket-partitioned writes -----
__global__ __launch_bounds__(1024, 1)
void k_bscatter(const int* __restrict__ src, const int* __restrict__ dst,
                const int* __restrict__ hist, int* __restrict__ bcursor,
                unsigned int* __restrict__ epack) {
    __shared__ unsigned int sdata[EPB];  // 64 KB
    __shared__ int h[NBUCK];             // rank cursors
    __shared__ int lstart[NBUCK];
    __shared__ int gbase[NBUCK];
    __shared__ int ps[1024];
    int tid = threadIdx.x;
    long e0 = (long)blockIdx.x * EPB;
    int cnt = (N_EDGES - e0 < EPB) ? (int)(N_EDGES - e0) : EPB;

    size_t row = (size_t)blockIdx.x * NBUCK;
    int c0 = hist[row + 2 * tid];
    int c1 = hist[row + 2 * tid + 1];
    int s = c0 + c1;
    ps[tid] = s;
    __syncthreads();
    for (int off = 1; off < 1024; off <<= 1) {
        int v = (tid >= off) ? ps[tid - off] : 0;
        __syncthreads();
        ps[tid] += v;
        __syncthreads();
    }
    int run = ps[tid] - s;   // exclusive prefix
    lstart[2 * tid]     = run;
    lstart[2 * tid + 1] = run + c0;
    gbase[2 * tid]     = c0 ? atomicAdd(&bcursor[2 * tid], c0) : 0;
    gbase[2 * tid + 1] = c1 ? atomicAdd(&bcursor[2 * tid + 1], c1) : 0;
    h[2 * tid] = 0;
    h[2 * tid + 1] = 0;
    __syncthreads();

    // rank + place sorted-by-bucket in LDS
    for (int k = 0; k < EPB / 1024; k++) {
        long e = e0 + tid + k * 1024;
        if (e < N_EDGES) {
            int d = dst[e];
            int b = d / BNODES;
            unsigned int rec = ((unsigned int)(d - b * BNODES) << 21) |
                               (unsigned int)src[e];
            int r = atomicAdd(&h[b], 1);
            sdata[lstart[b] + r] = rec;
        }
    }
    __syncthreads();

    // stream out: consecutive positions -> consecutive global addresses
    for (int p = tid; p < cnt; p += 1024) {
        int lo = 0, hi = NBUCK - 1;
        while (lo < hi) {                 // largest b with lstart[b] <= p
            int mid = (lo + hi + 1) >> 1;
            if (lstart[mid] <= p) lo = mid; else hi = mid - 1;
        }
        epack[(size_t)gbase[lo] + (p - lstart[lo])] = sdata[p];
    }
}

// ---- pass 4: per-bucket CSR build in LDS + dinv + xs = (x+po)*dinv -------
__global__ void k_bbuild(const unsigned int* __restrict__ epack,
                         const int* __restrict__ bstart,
                         const float* __restrict__ x,
                         int* __restrict__ csr, int* __restrict__ rowptr,
                         float* __restrict__ dinv, float* __restrict__ xs) {
    __shared__ int sdeg[BNODES];
    __shared__ int scur[BNODES];
    __shared__ int ps[256];
    __shared__ int stage[CAP];
    __shared__ float spo[D_IN];
    int b = blockIdx.x, tid = threadIdx.x;
    if (tid < D_IN) spo[tid] = sinf((float)tid);
    int n0 = b * BNODES;
    int n1 = n0 + BNODES; if (n1 > N_NODES) n1 = N_NODES;
    int nn = n1 - n0;
    int e0 = bstart[b], e1 = bstart[b + 1];
    int cnt = e1 - e0;
    for (int t = tid; t < nn; t += 256) sdeg[t] = 0;
    __syncthreads();
    for (int p = tid; p < cnt; p += 256)
        atomicAdd(&sdeg[epack[e0 + p] >> 21], 1);
    __syncthreads();
    int i0 = tid * 3;
    int s = 0;
#pragma unroll
    for (int k = 0; k < 3; k++) { int i = i0 + k; if (i < nn) s += sdeg[i]; }
    ps[tid] = s;
    __syncthreads();
    for (int off = 1; off < 256; off <<= 1) {
        int v = (tid >= off) ? ps[tid - off] : 0;
        __syncthreads();
        ps[tid] += v;
        __syncthreads();
    }
    int run = ps[tid] - s;
#pragma unroll
    for (int k = 0; k < 3; k++) {
        int i = i0 + k;
        if (i < nn) {
            int dg = sdeg[i];
            scur[i] = run;
            rowptr[n0 + i] = e0 + run;
            dinv[n0 + i] = rsqrtf((float)dg + 1.0f);
            run += dg;
        }
    }
    if (b == 0 && tid == 0) rowptr[N_NODES] = N_EDGES;
    __syncthreads();
    for (int p = tid; p < cnt; p += 256) {
        unsigned int u = epack[e0 + p];
        int dl = u >> 21;
        int sv = (int)(u & 0x1FFFFFu);
        int r = atomicAdd(&scur[dl], 1);
        if (r < CAP) stage[r] = sv;
        else         csr[e0 + r] = sv;   // overflow fallback (statistically never)
    }
    __syncthreads();
    int lim = cnt < CAP ? cnt : CAP;
    for (int p = tid; p < lim; p += 256) csr[e0 + p] = stage[p];
    for (int p = tid; p < nn * PADX; p += 256) {
        int ln = p >> 4;
        int k  = p & 15;
        float v = 0.f;
        if (k < D_IN)
            v = (x[(size_t)(n0 + ln) * D_IN + k] + spo[k]) *
                rsqrtf((float)sdeg[ln] + 1.0f);
        xs[(size_t)(n0 + ln) * PADX + k] = v;
    }
}

// ---- GCN1: aggregate 10-dim xs, then fused W1+b1 -> gelu -> W2 -> *dinv --
__global__ void k_agg1(const int* __restrict__ rowptr, const int* __restrict__ csr,
                       const float* __restrict__ xs, const float* __restrict__ dinv,
                       const float* __restrict__ W1, const float* __restrict__ b1,
                       const float* __restrict__ W2, float* __restrict__ hs2p) {
    __shared__ float sW1[D_IN * D_H];
    __shared__ float sb1[D_H];
    __shared__ float sW2[D_H * D_ENCC];
    __shared__ float sy[64][10];
    __shared__ float part[320][5];
    int tid = threadIdx.x;
    if      (tid < 200) sW1[tid] = W1[tid];
    else if (tid < 220) sb1[tid - 200] = b1[tid - 200];
    else                sW2[tid - 220] = W2[tid - 220];
    long t = (long)blockIdx.x * 320 + tid;
    bool act = t < (long)N_NODES * 5;
    int i = (int)(t / 5);
    int c = tid % 5;
    int ln = tid / 5;
    float2 acc = make_float2(0.f, 0.f);
    float di = 0.f;
    if (act) {
        acc = *(const float2*)(xs + (size_t)i * PADX + c * 2);
        int r0 = rowptr[i], r1 = rowptr[i + 1];
        for (int j = r0; j < r1; j++) {
            int s = csr[j];
            const float2 v = *(const float2*)(xs + (size_t)s * PADX + c * 2);
            acc.x += v.x; acc.y += v.y;
        }
        di = dinv[i];
    }
    __syncthreads();
    sy[ln][c * 2]     = di * acc.x;
    sy[ln][c * 2 + 1] = di * acc.y;
    __syncthreads();
    float y[10];
#pragma unroll
    for (int k = 0; k < 10; k++) y[k] = sy[ln][k];
    float p0 = 0.f, p1 = 0.f, p2 = 0.f, p3 = 0.f, p4 = 0.f;
#pragma unroll
    for (int jj = 0; jj < 4; jj++) {
        int j = c * 4 + jj;
        float tv = sb1[j];
#pragma unroll
        for (int k = 0; k < 10; k++) tv += y[k] * sW1[k * D_H + j];
        float g = gelu_exact(tv);
        p0 += g * sW2[j * 5 + 0]; p1 += g * sW2[j * 5 + 1]; p2 += g * sW2[j * 5 + 2];
        p3 += g * sW2[j * 5 + 3]; p4 += g * sW2[j * 5 + 4];
    }
    part[tid][0] = p0; part[tid][1] = p1; part[tid][2] = p2;
    part[tid][3] = p3; part[tid][4] = p4;
    __syncthreads();
    if (act) {
        int q = ln * 5;
        float sm = part[q][c] + part[q + 1][c] + part[q + 2][c]
                 + part[q + 3][c] + part[q + 4][c];
        hs2p[(size_t)i * PADH + c] = di * sm;
    }
}

// ---- GCN2 gather-aggregate + GELU (32B-padded rows) ----------------------
__global__ void k_agg2(const int* __restrict__ rowptr, const int* __restrict__ csr,
                       const float* __restrict__ hs2p, const float* __restrict__ dinv,
                       const float* __restrict__ b2, float* __restrict__ h2) {
    long t = (long)blockIdx.x * blockDim.x + threadIdx.x;
    if (t >= (long)N_NODES * 5) return;
    int i = (int)(t / 5);
    int c = (int)(t % 5);
    float acc = hs2p[(size_t)i * PADH + c];
    int r0 = rowptr[i], r1 = rowptr[i + 1];
    for (int j = r0; j < r1; j++)
        acc += hs2p[(size_t)csr[j] * PADH + c];
    h2[(size_t)i * 5 + c] = gelu_exact(dinv[i] * acc + b2[c]);
}

// ---- dense tail ----------------------------------------------------------
__global__ void k_dense(const float* __restrict__ h2,
                        const float* __restrict__ We, const float* __restrict__ be,
                        const float* __restrict__ Wd, const float* __restrict__ bd,
                        const float* __restrict__ Wr, const float* __restrict__ br,
                        float* __restrict__ out) {
    __shared__ float sWe[900], sWd[1800], sWr[210];
    __shared__ float sbe[30], sbd[60], sbr[7];
    for (int t = threadIdx.x; t < 900;  t += blockDim.x) sWe[t] = We[t];
    for (int t = threadIdx.x; t < 1800; t += blockDim.x) sWd[t] = Wd[t];
    for (int t = threadIdx.x; t < 210;  t += blockDim.x) sWr[t] = Wr[t];
    if (threadIdx.x < 30) sbe[threadIdx.x] = be[threadIdx.x];
    if (threadIdx.x >= 64  && threadIdx.x < 124) sbd[threadIdx.x - 64]  = bd[threadIdx.x - 64];
    if (threadIdx.x >= 128 && threadIdx.x < 135) sbr[threadIdx.x - 128] = br[threadIdx.x - 128];
    __syncthreads();
    int b = blockIdx.x * blockDim.x + threadIdx.x;
    if (b >= B_ROWS) return;

    float r[30];
#pragma unroll
    for (int k = 0; k < 30; k++) r[k] = h2[(size_t)b * 30 + k];

    float enc[30];
#pragma unroll
    for (int j = 0; j < 30; j++) {
        float a = sbe[j];
#pragma unroll
        for (int k = 0; k < 30; k++) a += r[k] * sWe[k * 30 + j];
        enc[j] = a;
    }

    float* x1o  = out;
    float* enco = out + (size_t)B_ROWS * 7;
    float* outo = out + (size_t)B_ROWS * 37;

#pragma unroll
    for (int j = 0; j < 30; j++) enco[(size_t)b * 30 + j] = enc[j];

#pragma unroll
    for (int k = 0; k < 30; k++) r[k] = gelu_exact(enc[k]);
#pragma unroll
    for (int j = 0; j < 60; j++) {
        float a = sbd[j];
#pragma unroll
        for (int k = 0; k < 30; k++) a += r[k] * sWd[k * 60 + j];
        outo[(size_t)b * 60 + j] = a;
    }
#pragma unroll
    for (int j = 0; j < 7; j++) {
        float a = sbr[j];
#pragma unroll
        for (int k = 0; k < 30; k++) a += enc[k] * sWr[k * 7 + j];
        x1o[(size_t)b * 7 + j] = a;
    }
}

extern "C" void kernel_launch(void* const* d_in, const int* in_sizes, int n_in,
                              void* d_out, int out_size, void* d_ws, size_t ws_size,
                              hipStream_t stream) {
    const float* x   = (const float*)d_in[0];
    const int*   ei  = (const int*)d_in[1];
    const int*   src = ei;
    const int*   dst = ei + N_EDGES;
    const float* W1  = (const float*)d_in[2];
    const float* b1  = (const float*)d_in[3];
    const float* W2  = (const float*)d_in[4];
    const float* b2  = (const float*)d_in[5];
    const float* We  = (const float*)d_in[6];
    const float* be  = (const float*)d_in[7];
    const float* Wd  = (const float*)d_in[8];
    const float* bd  = (const float*)d_in[9];
    const float* Wr  = (const float*)d_in[10];
    const float* br  = (const float*)d_in[11];

    char* ws = (char*)d_ws;
    // epack (48 MB) consumed by k_bbuild, then reused as hs2p (38.4 MB).
    unsigned int* epack = (unsigned int*)ws;  ws += sizeof(unsigned int) * (size_t)N_EDGES;
    float* hs2p  = (float*)epack;
    int*   csr    = (int*)ws;   ws += sizeof(int) * (size_t)N_EDGES;
    int*   rowptr = (int*)ws;   ws += sizeof(int) * (N_NODES + 16);
    float* dinv   = (float*)ws; ws += sizeof(float) * N_NODES;
    float* xs     = (float*)ws; ws += sizeof(float) * (size_t)N_NODES * PADX;
    float* h2     = (float*)ws; ws += sizeof(float) * (size_t)N_NODES * D_ENCC;
    int*   hist   = (int*)ws;   ws += sizeof(int) * (size_t)NBLK_E * NBUCK;
    int*   gcount = (int*)ws;   ws += sizeof(int) * NBUCK;
    int*   bstart = (int*)ws;   ws += sizeof(int) * (NBUCK + 16);
    int*   bcursor= (int*)ws;   ws += sizeof(int) * NBUCK;

    hipMemsetAsync(gcount, 0, sizeof(int) * NBUCK, stream);

    k_bhist   <<<NBLK_E, 256, 0, stream>>>(dst, gcount, hist);
    k_bscan   <<<1, 256, 0, stream>>>(gcount, bstart, bcursor);
    k_bscatter<<<NBLK_E, 1024, 0, stream>>>(src, dst, hist, bcursor, epack);
    k_bbuild  <<<NBUCK, 256, 0, stream>>>(epack, bstart, x, csr, rowptr, dinv, xs);
    k_agg1    <<<(int)(((long)N_NODES * 5) / 320), 320, 0, stream>>>(rowptr, csr, xs,
                                                                     dinv, W1, b1, W2, hs2p);
    k_agg2    <<<(int)(((long)N_NODES * 5 + 255) / 256), 256, 0, stream>>>(rowptr, csr,
                                                                           hs2p, dinv, b2, h2);
    k_dense   <<<(B_ROWS + 255) / 256, 256, 0, stream>>>(h2, We, be, Wd, bd, Wr, br,
                                                         (float*)d_out);
}